// Round 2
// baseline (939.669 us; speedup 1.0000x reference)
//
#include <hip/hip_runtime.h>

typedef unsigned short u16;
typedef unsigned int u32;

#define LL 512
#define DIMC 64
#define HIDC 128

typedef __attribute__((ext_vector_type(8))) __bf16 bf16x8;
typedef __attribute__((ext_vector_type(4))) float f32x4;

__device__ __forceinline__ u16 f2bf(float f) {
  u32 u = __float_as_uint(f);
  u = u + 0x7FFFu + ((u >> 16) & 1u);   // RNE
  return (u16)(u >> 16);
}
__device__ __forceinline__ float bf2f(u32 us) {
  return __uint_as_float(us << 16);
}
__device__ __forceinline__ float sigm(float x) {
  return 1.0f / (1.0f + __expf(-x));
}

// ---- kernel A: LN + right/og projections (MFMA), one chunk of rows ------
// grid CHUNK+8 (block -> row p = k0 + bid), 256 threads (4 waves).
// Writes right into ring slot (bid); writes og (d_out) only for p in chunk.
extern "C" __global__ void __launch_bounds__(256, 2)
kernA(const float* __restrict__ x, const int* __restrict__ smask,
      const float* __restrict__ ns, const float* __restrict__ nb,
      const float* __restrict__ Wr, const float* __restrict__ br,
      const float* __restrict__ Wrg, const float* __restrict__ brg,
      const float* __restrict__ Wog, const float* __restrict__ bog,
      u16* __restrict__ ring, u16* og, int k0, int i0, int chunk)
{
  __shared__ u16 sWT[384 * 64];   // 48KB, swizzled rows of 128B
  __shared__ u16 sA[64 * 64];     // 8KB, swizzled
  const int p = k0 + blockIdx.x;
  if (p < 0 || p >= LL) return;
  const int slot = blockIdx.x;
  const bool store_og = (p >= i0) && (p < i0 + chunk);
  const int t = threadIdx.x;
  const int lane = t & 63;
  const int wave = t >> 6;
  const int l15 = lane & 15, l4 = lane >> 4;

  { // stage weights f32 global -> swizzled bf16 LDS (coalesced reads)
#pragma unroll
    for (int w = 0; w < 3; ++w) {
      const float* W = (w == 0) ? Wr : (w == 1 ? Wrg : Wog);
      const int nbase = w * 128;
      for (int idx = t; idx < 64 * 128; idx += 256) {
        int k = idx >> 7, h = idx & 127;
        int row = nbase + h;
        sWT[row * 64 + (((k >> 3) ^ (row & 7)) << 3) + (k & 7)] = f2bf(W[idx]);
      }
    }
  }

  const float mrow = (float)smask[p];
  const int ql = t >> 2, qc = t & 3;      // pair-in-tile, dim-quarter
  float4 nsv[4], nbv[4];
#pragma unroll
  for (int j = 0; j < 4; j++) {
    nsv[j] = *(const float4*)(ns + qc * 16 + j * 4);
    nbv[j] = *(const float4*)(nb + qc * 16 + j * 4);
  }
  float brv[2], brgv[2], bogv[2];
#pragma unroll
  for (int fp = 0; fp < 2; fp++) {
    int h = wave * 32 + fp * 16 + l15;
    brv[fp] = br[h]; brgv[fp] = brg[h]; bogv[fp] = bog[h];
  }

  for (int tile = 0; tile < 8; ++tile) {
    const int q0 = tile * 64;
    { // ---- LN -> sA (bf16, swizzled)
      const int q = q0 + ql;
      const float* xp = x + ((size_t)p * LL + q) * DIMC + qc * 16;
      float4 xv[4];
      float s = 0.f, ss = 0.f;
#pragma unroll
      for (int j = 0; j < 4; j++) {
        xv[j] = *(const float4*)(xp + j * 4);
        s += xv[j].x + xv[j].y + xv[j].z + xv[j].w;
        ss += xv[j].x * xv[j].x + xv[j].y * xv[j].y + xv[j].z * xv[j].z + xv[j].w * xv[j].w;
      }
      s += __shfl_xor(s, 1); ss += __shfl_xor(ss, 1);
      s += __shfl_xor(s, 2); ss += __shfl_xor(ss, 2);
      const float mean = s * (1.f / 64.f);
      const float var = ss * (1.f / 64.f) - mean * mean;
      const float rstd = rsqrtf(var + 1e-6f);
      u16 xb[16];
#pragma unroll
      for (int j = 0; j < 4; j++) {
        xb[j*4+0] = f2bf((xv[j].x - mean) * rstd * nsv[j].x + nbv[j].x);
        xb[j*4+1] = f2bf((xv[j].y - mean) * rstd * nsv[j].y + nbv[j].y);
        xb[j*4+2] = f2bf((xv[j].z - mean) * rstd * nsv[j].z + nbv[j].z);
        xb[j*4+3] = f2bf((xv[j].w - mean) * rstd * nsv[j].w + nbv[j].w);
      }
      uint4 c0, c1;
      c0.x = (u32)xb[0]  | ((u32)xb[1]  << 16);
      c0.y = (u32)xb[2]  | ((u32)xb[3]  << 16);
      c0.z = (u32)xb[4]  | ((u32)xb[5]  << 16);
      c0.w = (u32)xb[6]  | ((u32)xb[7]  << 16);
      c1.x = (u32)xb[8]  | ((u32)xb[9]  << 16);
      c1.y = (u32)xb[10] | ((u32)xb[11] << 16);
      c1.z = (u32)xb[12] | ((u32)xb[13] << 16);
      c1.w = (u32)xb[14] | ((u32)xb[15] << 16);
      char* rowp = (char*)sA + ql * 128;
      *(uint4*)(rowp + (((qc * 2 + 0) ^ (ql & 7)) << 4)) = c0;
      *(uint4*)(rowp + (((qc * 2 + 1) ^ (ql & 7)) << 4)) = c1;
    }
    __syncthreads();
    // ---- MFMA: [64 pairs x 64k] @ [64k x 384n], wave owns 32 cols of each group
    f32x4 acc[4][6];
    f32x4 zero = {0.f, 0.f, 0.f, 0.f};
#pragma unroll
    for (int m = 0; m < 4; m++)
#pragma unroll
      for (int f = 0; f < 6; f++) acc[m][f] = zero;
#pragma unroll
    for (int ks = 0; ks < 2; ks++) {
      bf16x8 av[4];
#pragma unroll
      for (int m = 0; m < 4; m++) {
        int row = m * 16 + l15;
        int ch = (ks * 4 + l4) ^ (row & 7);
        av[m] = *(const bf16x8*)((const char*)sA + row * 128 + (ch << 4));
      }
#pragma unroll
      for (int f = 0; f < 6; f++) {
        int g = f >> 1, fp = f & 1;
        int n = g * 128 + wave * 32 + fp * 16 + l15;
        int ch = (ks * 4 + l4) ^ (n & 7);
        bf16x8 bv = *(const bf16x8*)((const char*)sWT + n * 128 + (ch << 4));
#pragma unroll
        for (int m = 0; m < 4; m++)
          acc[m][f] = __builtin_amdgcn_mfma_f32_16x16x32_bf16(av[m], bv, acc[m][f], 0, 0, 0);
      }
    }
    __syncthreads();   // all LDS reads done before next tile's LN writes
    // ---- epilogue: bias, mask, sigmoid gates; store right(ring)/og bf16
#pragma unroll
    for (int m = 0; m < 4; m++) {
      float mv[4];
#pragma unroll
      for (int r = 0; r < 4; r++)
        mv[r] = mrow * (float)smask[q0 + m * 16 + l4 * 4 + r];
#pragma unroll
      for (int fp = 0; fp < 2; fp++) {
        const int h = wave * 32 + fp * 16 + l15;
        f32x4 lin = acc[m][fp];
        f32x4 gat = acc[m][2 + fp];
        f32x4 ogv = acc[m][4 + fp];
#pragma unroll
        for (int r = 0; r < 4; r++) {
          int qq = q0 + m * 16 + l4 * 4 + r;
          float rv = (lin[r] + brv[fp]) * mv[r] * sigm(gat[r] + brgv[fp]);
          ring[((size_t)slot * LL + qq) * HIDC + h] = f2bf(rv);
          if (store_og) {
            float ov = sigm(ogv[r] + bogv[fp]);
            og[((size_t)p * LL + qq) * HIDC + h] = f2bf(ov);
          }
        }
      }
    }
  }
}

// ---- kernel A2: left on the 9 diagonals only ----------------------------
// grid 512 (block = output row i), 64 threads (1 wave). Full Lbuf (2.25MB).
extern "C" __global__ void kernA2(const float* __restrict__ x, const int* __restrict__ smask,
                                  const float* __restrict__ ns, const float* __restrict__ nb,
                                  const float* __restrict__ Wl, const float* __restrict__ bl,
                                  const float* __restrict__ Wlg, const float* __restrict__ blg,
                                  float* __restrict__ Lbuf)
{
  __shared__ float sxn[64];
  const int i = blockIdx.x;
  const int lane = threadIdx.x;
  const float mi = (float)smask[i];
  const float nsv = ns[lane], nbv = nb[lane];
  for (int d = 0; d < 9; d++) {
    const int p = i + d - 4;
    float* outp = Lbuf + ((size_t)i * 9 + d) * HIDC;
    if (p >= 0 && p < LL) {
      float xv = x[((size_t)p * LL + i) * DIMC + lane];
      float s = xv, ss = xv * xv;
#pragma unroll
      for (int o = 1; o < 64; o <<= 1) { s += __shfl_xor(s, o); ss += __shfl_xor(ss, o); }
      float mean = s * (1.f / 64.f);
      float rstd = rsqrtf(ss * (1.f / 64.f) - mean * mean + 1e-6f);
      sxn[lane] = (xv - mean) * rstd * nsv + nbv;
      __syncthreads();
      float mv = mi * (float)smask[p];
#pragma unroll
      for (int hh = 0; hh < 2; hh++) {
        int h = lane + hh * 64;
        float dl = 0.f, dg = 0.f;
        for (int k = 0; k < 64; k++) {
          float xk = sxn[k];
          dl = fmaf(xk, Wl[k * HIDC + h], dl);
          dg = fmaf(xk, Wlg[k * HIDC + h], dg);
        }
        outp[h] = (dl + bl[h]) * mv * sigm(dg + blg[h]);
      }
      __syncthreads();
    } else {
      outp[lane] = 0.f;
      outp[lane + 64] = 0.f;
    }
  }
}

// ---- kernel B: banded product + LN + gate + Wo projection, one chunk ----
// grid chunk*8 (block = (i = i0 + bid>>3, j-tile = bid&7)), 256 threads.
// og aliases d_out; each block reads only its own (i, j-tile) og rows and
// overwrites exactly those rows with the final output (ordered by barrier).
extern "C" __global__ void __launch_bounds__(256, 4)
kernB(const u16* __restrict__ ring, const u16* og,
      const float* __restrict__ Lbuf, const float* __restrict__ Wo,
      const float* __restrict__ osc, const float* __restrict__ obi,
      const float* __restrict__ bo, float* out, int k0, int i0)
{
  __shared__ u16 sWo[64 * 128];   // 16KB swizzled
  __shared__ u16 sA[64 * 128];    // 16KB swizzled
  __shared__ float sLb[9 * 128];
  const int bid = blockIdx.x;
  const int i = i0 + (bid >> 3), j0 = (bid & 7) * 64;
  const int t = threadIdx.x;
  const int lane = t & 63, wave = t >> 6;
  const int l15 = lane & 15, l4 = lane >> 4;
  { // stage Wo f32 -> swizzled bf16 (WoT[n=d][k], n<64, k<128)
    for (int idx = t; idx < 128 * 64; idx += 256) {
      int k = idx >> 6, d = idx & 63;
      sWo[d * 128 + (((k >> 3) ^ (d & 7)) << 3) + (k & 7)] = f2bf(Wo[idx]);
    }
    const float* lb = Lbuf + (size_t)i * (9 * HIDC);
    for (int idx = t; idx < 9 * HIDC; idx += 256) sLb[idx] = lb[idx];
  }
  __syncthreads();
  const int j = t >> 2, hq = t & 3, h0 = hq * 32;
  float acc[32];
#pragma unroll
  for (int e = 0; e < 32; e++) acc[e] = 0.f;
  for (int d = 0; d < 9; d++) {
    const int k = i + d - 4;
    if (k < 0 || k >= LL) continue;
    const int slot = k - k0;
    const u16* rp = ring + ((size_t)slot * LL + j0 + j) * HIDC + h0;
#pragma unroll
    for (int c4 = 0; c4 < 4; c4++) {
      uint4 rv = *(const uint4*)(rp + c4 * 8);
      const float4 lb0 = *(const float4*)(sLb + d * 128 + h0 + c4 * 8);
      const float4 lb1 = *(const float4*)(sLb + d * 128 + h0 + c4 * 8 + 4);
      acc[c4*8+0] = fmaf(lb0.x, bf2f(rv.x & 0xffff), acc[c4*8+0]);
      acc[c4*8+1] = fmaf(lb0.y, bf2f(rv.x >> 16),    acc[c4*8+1]);
      acc[c4*8+2] = fmaf(lb0.z, bf2f(rv.y & 0xffff), acc[c4*8+2]);
      acc[c4*8+3] = fmaf(lb0.w, bf2f(rv.y >> 16),    acc[c4*8+3]);
      acc[c4*8+4] = fmaf(lb1.x, bf2f(rv.z & 0xffff), acc[c4*8+4]);
      acc[c4*8+5] = fmaf(lb1.y, bf2f(rv.z >> 16),    acc[c4*8+5]);
      acc[c4*8+6] = fmaf(lb1.z, bf2f(rv.w & 0xffff), acc[c4*8+6]);
      acc[c4*8+7] = fmaf(lb1.w, bf2f(rv.w >> 16),    acc[c4*8+7]);
    }
  }
  // LN over 128 (4 threads per j)
  float s = 0.f, ss = 0.f;
#pragma unroll
  for (int e = 0; e < 32; e++) { s += acc[e]; ss += acc[e] * acc[e]; }
  s += __shfl_xor(s, 1); ss += __shfl_xor(ss, 1);
  s += __shfl_xor(s, 2); ss += __shfl_xor(ss, 2);
  const float mean = s * (1.f / 128.f);
  const float rstd = rsqrtf(ss * (1.f / 128.f) - mean * mean + 1e-6f);
  const u16* ogp = og + ((size_t)i * LL + j0 + j) * HIDC + h0;
  char* rowp = (char*)sA + j * 256;
#pragma unroll
  for (int c4 = 0; c4 < 4; c4++) {
    const float4 o0 = *(const float4*)(osc + h0 + c4 * 8);
    const float4 o1 = *(const float4*)(osc + h0 + c4 * 8 + 4);
    const float4 b0 = *(const float4*)(obi + h0 + c4 * 8);
    const float4 b1 = *(const float4*)(obi + h0 + c4 * 8 + 4);
    uint4 gv = *(const uint4*)(ogp + c4 * 8);
    float v0 = ((acc[c4*8+0] - mean) * rstd * o0.x + b0.x) * bf2f(gv.x & 0xffff);
    float v1 = ((acc[c4*8+1] - mean) * rstd * o0.y + b0.y) * bf2f(gv.x >> 16);
    float v2 = ((acc[c4*8+2] - mean) * rstd * o0.z + b0.z) * bf2f(gv.y & 0xffff);
    float v3 = ((acc[c4*8+3] - mean) * rstd * o0.w + b0.w) * bf2f(gv.y >> 16);
    float v4 = ((acc[c4*8+4] - mean) * rstd * o1.x + b1.x) * bf2f(gv.z & 0xffff);
    float v5 = ((acc[c4*8+5] - mean) * rstd * o1.y + b1.y) * bf2f(gv.z >> 16);
    float v6 = ((acc[c4*8+6] - mean) * rstd * o1.z + b1.z) * bf2f(gv.w & 0xffff);
    float v7 = ((acc[c4*8+7] - mean) * rstd * o1.w + b1.w) * bf2f(gv.w >> 16);
    uint4 pk;
    pk.x = (u32)f2bf(v0) | ((u32)f2bf(v1) << 16);
    pk.y = (u32)f2bf(v2) | ((u32)f2bf(v3) << 16);
    pk.z = (u32)f2bf(v4) | ((u32)f2bf(v5) << 16);
    pk.w = (u32)f2bf(v6) | ((u32)f2bf(v7) << 16);
    *(uint4*)(rowp + (((hq * 4 + c4) ^ (j & 7)) << 4)) = pk;
  }
  __syncthreads();   // og fully read; sA ready
  f32x4 acc2[4];
  f32x4 zero = {0.f, 0.f, 0.f, 0.f};
#pragma unroll
  for (int m = 0; m < 4; m++) acc2[m] = zero;
#pragma unroll
  for (int ks = 0; ks < 4; ks++) {
    int n = wave * 16 + l15;
    int chb = (ks * 4 + l4) ^ (n & 7);
    bf16x8 bv = *(const bf16x8*)((const char*)sWo + n * 256 + (chb << 4));
#pragma unroll
    for (int m = 0; m < 4; m++) {
      int row = m * 16 + l15;
      int cha = (ks * 4 + l4) ^ (row & 7);
      bf16x8 av = *(const bf16x8*)((const char*)sA + row * 256 + (cha << 4));
      acc2[m] = __builtin_amdgcn_mfma_f32_16x16x32_bf16(av, bv, acc2[m], 0, 0, 0);
    }
  }
  const int dim = wave * 16 + l15;
  const float bov = bo[dim];
#pragma unroll
  for (int m = 0; m < 4; m++) {
#pragma unroll
    for (int r = 0; r < 4; r++) {
      int jj = j0 + m * 16 + l4 * 4 + r;
      out[((size_t)i * LL + jj) * DIMC + dim] = acc2[m][r] + bov;
    }
  }
}

extern "C" void kernel_launch(void* const* d_in, const int* in_sizes, int n_in,
                              void* d_out, int out_size, void* d_ws, size_t ws_size,
                              hipStream_t stream) {
  const float* x    = (const float*)d_in[0];
  const int*   sm   = (const int*)d_in[1];
  const float* ns   = (const float*)d_in[2];
  const float* nb   = (const float*)d_in[3];
  const float* Wl   = (const float*)d_in[4];
  const float* bl   = (const float*)d_in[5];
  const float* Wr   = (const float*)d_in[6];
  const float* br   = (const float*)d_in[7];
  const float* Wlg  = (const float*)d_in[8];
  const float* blg  = (const float*)d_in[9];
  const float* Wrg  = (const float*)d_in[10];
  const float* brg  = (const float*)d_in[11];
  const float* Wog  = (const float*)d_in[12];
  const float* bog  = (const float*)d_in[13];
  const float* osc  = (const float*)d_in[14];
  const float* obi  = (const float*)d_in[15];
  const float* Wo   = (const float*)d_in[16];
  const float* bo   = (const float*)d_in[17];

  // ws layout (provably small; was 69.5MB in round-1 which overran ws_size
  // and clobbered neighboring buffers -> post-timing drift):
  //   Lbuf f32 [512*9*128]            : 2,359,296 B
  //   right ring bf16 [(CHUNK+8)*512*128]
  // CHUNK=256 -> total ~36.1 MB; fallback CHUNK=64 -> ~11.8 MB.
  const size_t LBUF_BYTES = (size_t)LL * 9 * HIDC * 4;
  char* ws = (char*)d_ws;
  float* Lbuf = (float*)ws;
  u16* ring = (u16*)(ws + LBUF_BYTES);

  int CHUNK = 256;
  if (ws_size < LBUF_BYTES + (size_t)(256 + 8) * LL * HIDC * 2) CHUNK = 64;
  u16* ogB = (u16*)d_out;   // og lives in d_out, chunk-local, consumed by kernB

  kernA2<<<512, 64, 0, stream>>>(x, sm, ns, nb, Wl, bl, Wlg, blg, Lbuf);
  for (int i0 = 0; i0 < LL; i0 += CHUNK) {
    const int k0 = i0 - 4;
    kernA<<<CHUNK + 8, 256, 0, stream>>>(x, sm, ns, nb, Wr, br, Wrg, brg,
                                         Wog, bog, ring, ogB, k0, i0, CHUNK);
    kernB<<<CHUNK * 8, 256, 0, stream>>>(ring, ogB, Lbuf, Wo, osc, obi, bo,
                                         (float*)d_out, k0, i0);
  }
}

// Round 3
// 222.695 us; speedup vs baseline: 4.2195x; 4.2195x over previous
//
#include <hip/hip_runtime.h>

typedef unsigned short u16;
typedef unsigned int u32;

#define LL 512
#define DIMC 64
#define HIDC 128

typedef __attribute__((ext_vector_type(8))) __bf16 bf16x8;
typedef __attribute__((ext_vector_type(4))) float f32x4;

__device__ __forceinline__ u16 f2bf(float f) {
  u32 u = __float_as_uint(f);
  u = u + 0x7FFFu + ((u >> 16) & 1u);   // RNE
  return (u16)(u >> 16);
}
__device__ __forceinline__ float bf2f(u32 us) {
  return __uint_as_float(us << 16);
}
__device__ __forceinline__ float sigm(float x) {
  return 1.0f / (1.0f + __expf(-x));
}

// ---- kernel A: LN + right/og projections (MFMA), one chunk of rows ------
// grid CHUNK+8 (block -> row p = k0 + bid), 256 threads (4 waves).
// Writes right into ring slot (bid); writes og (d_out) only for p in chunk.
extern "C" __global__ void __launch_bounds__(256, 2)
kernA(const float* __restrict__ x, const int* __restrict__ smask,
      const float* __restrict__ ns, const float* __restrict__ nb,
      const float* __restrict__ Wr, const float* __restrict__ br,
      const float* __restrict__ Wrg, const float* __restrict__ brg,
      const float* __restrict__ Wog, const float* __restrict__ bog,
      u16* __restrict__ ring, u16* og, int k0, int i0, int chunk)
{
  __shared__ u16 sWT[384 * 64];   // 48KB, swizzled rows of 128B
  __shared__ u16 sA[64 * 64];     // 8KB, swizzled
  const int p = k0 + blockIdx.x;
  if (p < 0 || p >= LL) return;
  const int slot = blockIdx.x;
  const bool store_og = (p >= i0) && (p < i0 + chunk);
  const int t = threadIdx.x;
  const int lane = t & 63;
  const int wave = t >> 6;
  const int l15 = lane & 15, l4 = lane >> 4;

  { // stage weights f32 global -> swizzled bf16 LDS (coalesced reads)
#pragma unroll
    for (int w = 0; w < 3; ++w) {
      const float* W = (w == 0) ? Wr : (w == 1 ? Wrg : Wog);
      const int nbase = w * 128;
      for (int idx = t; idx < 64 * 128; idx += 256) {
        int k = idx >> 7, h = idx & 127;
        int row = nbase + h;
        sWT[row * 64 + (((k >> 3) ^ (row & 7)) << 3) + (k & 7)] = f2bf(W[idx]);
      }
    }
  }

  const float mrow = (float)smask[p];
  const int ql = t >> 2, qc = t & 3;      // pair-in-tile, dim-quarter
  float4 nsv[4], nbv[4];
#pragma unroll
  for (int j = 0; j < 4; j++) {
    nsv[j] = *(const float4*)(ns + qc * 16 + j * 4);
    nbv[j] = *(const float4*)(nb + qc * 16 + j * 4);
  }
  float brv[2], brgv[2], bogv[2];
#pragma unroll
  for (int fp = 0; fp < 2; fp++) {
    int h = wave * 32 + fp * 16 + l15;
    brv[fp] = br[h]; brgv[fp] = brg[h]; bogv[fp] = bog[h];
  }

  for (int tile = 0; tile < 8; ++tile) {
    const int q0 = tile * 64;
    { // ---- LN -> sA (bf16, swizzled)
      const int q = q0 + ql;
      const float* xp = x + ((size_t)p * LL + q) * DIMC + qc * 16;
      float4 xv[4];
      float s = 0.f, ss = 0.f;
#pragma unroll
      for (int j = 0; j < 4; j++) {
        xv[j] = *(const float4*)(xp + j * 4);
        s += xv[j].x + xv[j].y + xv[j].z + xv[j].w;
        ss += xv[j].x * xv[j].x + xv[j].y * xv[j].y + xv[j].z * xv[j].z + xv[j].w * xv[j].w;
      }
      s += __shfl_xor(s, 1); ss += __shfl_xor(ss, 1);
      s += __shfl_xor(s, 2); ss += __shfl_xor(ss, 2);
      const float mean = s * (1.f / 64.f);
      const float var = ss * (1.f / 64.f) - mean * mean;
      const float rstd = rsqrtf(var + 1e-6f);
      u16 xb[16];
#pragma unroll
      for (int j = 0; j < 4; j++) {
        xb[j*4+0] = f2bf((xv[j].x - mean) * rstd * nsv[j].x + nbv[j].x);
        xb[j*4+1] = f2bf((xv[j].y - mean) * rstd * nsv[j].y + nbv[j].y);
        xb[j*4+2] = f2bf((xv[j].z - mean) * rstd * nsv[j].z + nbv[j].z);
        xb[j*4+3] = f2bf((xv[j].w - mean) * rstd * nsv[j].w + nbv[j].w);
      }
      uint4 c0, c1;
      c0.x = (u32)xb[0]  | ((u32)xb[1]  << 16);
      c0.y = (u32)xb[2]  | ((u32)xb[3]  << 16);
      c0.z = (u32)xb[4]  | ((u32)xb[5]  << 16);
      c0.w = (u32)xb[6]  | ((u32)xb[7]  << 16);
      c1.x = (u32)xb[8]  | ((u32)xb[9]  << 16);
      c1.y = (u32)xb[10] | ((u32)xb[11] << 16);
      c1.z = (u32)xb[12] | ((u32)xb[13] << 16);
      c1.w = (u32)xb[14] | ((u32)xb[15] << 16);
      char* rowp = (char*)sA + ql * 128;
      *(uint4*)(rowp + (((qc * 2 + 0) ^ (ql & 7)) << 4)) = c0;
      *(uint4*)(rowp + (((qc * 2 + 1) ^ (ql & 7)) << 4)) = c1;
    }
    __syncthreads();
    // ---- MFMA: [64 pairs x 64k] @ [64k x 384n], wave owns 32 cols of each group
    f32x4 acc[4][6];
    f32x4 zero = {0.f, 0.f, 0.f, 0.f};
#pragma unroll
    for (int m = 0; m < 4; m++)
#pragma unroll
      for (int f = 0; f < 6; f++) acc[m][f] = zero;
#pragma unroll
    for (int ks = 0; ks < 2; ks++) {
      bf16x8 av[4];
#pragma unroll
      for (int m = 0; m < 4; m++) {
        int row = m * 16 + l15;
        int ch = (ks * 4 + l4) ^ (row & 7);
        av[m] = *(const bf16x8*)((const char*)sA + row * 128 + (ch << 4));
      }
#pragma unroll
      for (int f = 0; f < 6; f++) {
        int g = f >> 1, fp = f & 1;
        int n = g * 128 + wave * 32 + fp * 16 + l15;
        int ch = (ks * 4 + l4) ^ (n & 7);
        bf16x8 bv = *(const bf16x8*)((const char*)sWT + n * 128 + (ch << 4));
#pragma unroll
        for (int m = 0; m < 4; m++)
          acc[m][f] = __builtin_amdgcn_mfma_f32_16x16x32_bf16(av[m], bv, acc[m][f], 0, 0, 0);
      }
    }
    __syncthreads();   // all LDS reads done before next tile's LN writes
    // ---- epilogue: bias, mask, sigmoid gates; store right(ring)/og bf16
#pragma unroll
    for (int m = 0; m < 4; m++) {
      float mv[4];
#pragma unroll
      for (int r = 0; r < 4; r++)
        mv[r] = mrow * (float)smask[q0 + m * 16 + l4 * 4 + r];
#pragma unroll
      for (int fp = 0; fp < 2; fp++) {
        const int h = wave * 32 + fp * 16 + l15;
        f32x4 lin = acc[m][fp];
        f32x4 gat = acc[m][2 + fp];
        f32x4 ogv = acc[m][4 + fp];
#pragma unroll
        for (int r = 0; r < 4; r++) {
          int qq = q0 + m * 16 + l4 * 4 + r;
          float rv = (lin[r] + brv[fp]) * mv[r] * sigm(gat[r] + brgv[fp]);
          ring[((size_t)slot * LL + qq) * HIDC + h] = f2bf(rv);
          if (store_og) {
            float ov = sigm(ogv[r] + bogv[fp]);
            og[((size_t)p * LL + qq) * HIDC + h] = f2bf(ov);
          }
        }
      }
    }
  }
}

// ---- kernel L: left on the 9 diagonals via MFMA -------------------------
// Flattened row space g = i*9 + d (i in [0,512), d in [0,9)), M = 4608.
// GEMM [4608 x 64k] @ [64k x 256n], n = [Wl(128) | Wlg(128)].
// grid 72 blocks x 256 threads, 64 rows per block. Replaces the round-2
// kernA2 which was 790us (84% of total): 1-wave blocks + 2304 dependent
// global scalar loads/thread, FETCH 204MB. Weights now staged once/block.
extern "C" __global__ void __launch_bounds__(256, 2)
kernL(const float* __restrict__ x, const int* __restrict__ smask,
      const float* __restrict__ ns, const float* __restrict__ nb,
      const float* __restrict__ Wl, const float* __restrict__ bl,
      const float* __restrict__ Wlg, const float* __restrict__ blg,
      float* __restrict__ Lbuf)
{
  __shared__ u16 sW[256 * 64];    // 32KB swizzled: rows 0..127 Wl_h, 128..255 Wlg_h
  __shared__ u16 sA[64 * 64];     // 8KB swizzled LN'd rows
  const int g0 = blockIdx.x * 64;
  const int t = threadIdx.x;
  const int lane = t & 63, wave = t >> 6;
  const int l15 = lane & 15, l4 = lane >> 4;

  { // stage Wl/Wlg f32 -> swizzled bf16
#pragma unroll
    for (int w = 0; w < 2; ++w) {
      const float* W = (w == 0) ? Wl : Wlg;
      const int nbase = w * 128;
      for (int idx = t; idx < 64 * 128; idx += 256) {
        int k = idx >> 7, h = idx & 127;
        int row = nbase + h;
        sW[row * 64 + (((k >> 3) ^ (row & 7)) << 3) + (k & 7)] = f2bf(W[idx]);
      }
    }
  }

  const int ql = t >> 2, qc = t & 3;     // row-in-tile, dim-quarter
  { // ---- LN -> sA: row g = g0+ql -> (i = g/9, d = g%9, p = i+d-4)
    const int g = g0 + ql;
    const int i = g / 9, d = g - 9 * i;
    int p = i + d - 4;
    p = (p < 0) ? 0 : (p > LL - 1 ? LL - 1 : p);   // clamp; invalid rows zeroed later
    const float* xp = x + ((size_t)p * LL + i) * DIMC + qc * 16;
    float4 xv[4];
    float s = 0.f, ss = 0.f;
#pragma unroll
    for (int j = 0; j < 4; j++) {
      xv[j] = *(const float4*)(xp + j * 4);
      s += xv[j].x + xv[j].y + xv[j].z + xv[j].w;
      ss += xv[j].x * xv[j].x + xv[j].y * xv[j].y + xv[j].z * xv[j].z + xv[j].w * xv[j].w;
    }
    s += __shfl_xor(s, 1); ss += __shfl_xor(ss, 1);
    s += __shfl_xor(s, 2); ss += __shfl_xor(ss, 2);
    const float mean = s * (1.f / 64.f);
    const float rstd = rsqrtf(ss * (1.f / 64.f) - mean * mean + 1e-6f);
    u16 xb[16];
#pragma unroll
    for (int j = 0; j < 4; j++) {
      const float4 nsv = *(const float4*)(ns + qc * 16 + j * 4);
      const float4 nbv = *(const float4*)(nb + qc * 16 + j * 4);
      xb[j*4+0] = f2bf((xv[j].x - mean) * rstd * nsv.x + nbv.x);
      xb[j*4+1] = f2bf((xv[j].y - mean) * rstd * nsv.y + nbv.y);
      xb[j*4+2] = f2bf((xv[j].z - mean) * rstd * nsv.z + nbv.z);
      xb[j*4+3] = f2bf((xv[j].w - mean) * rstd * nsv.w + nbv.w);
    }
    uint4 c0, c1;
    c0.x = (u32)xb[0]  | ((u32)xb[1]  << 16);
    c0.y = (u32)xb[2]  | ((u32)xb[3]  << 16);
    c0.z = (u32)xb[4]  | ((u32)xb[5]  << 16);
    c0.w = (u32)xb[6]  | ((u32)xb[7]  << 16);
    c1.x = (u32)xb[8]  | ((u32)xb[9]  << 16);
    c1.y = (u32)xb[10] | ((u32)xb[11] << 16);
    c1.z = (u32)xb[12] | ((u32)xb[13] << 16);
    c1.w = (u32)xb[14] | ((u32)xb[15] << 16);
    char* rowp = (char*)sA + ql * 128;
    *(uint4*)(rowp + (((qc * 2 + 0) ^ (ql & 7)) << 4)) = c0;
    *(uint4*)(rowp + (((qc * 2 + 1) ^ (ql & 7)) << 4)) = c1;
  }
  __syncthreads();
  // ---- MFMA: [64 rows x 64k] @ [64k x 256n], wave owns 32 cols per group
  f32x4 acc[4][4];
  f32x4 zero = {0.f, 0.f, 0.f, 0.f};
#pragma unroll
  for (int m = 0; m < 4; m++)
#pragma unroll
    for (int f = 0; f < 4; f++) acc[m][f] = zero;
#pragma unroll
  for (int ks = 0; ks < 2; ks++) {
    bf16x8 av[4];
#pragma unroll
    for (int m = 0; m < 4; m++) {
      int row = m * 16 + l15;
      int ch = (ks * 4 + l4) ^ (row & 7);
      av[m] = *(const bf16x8*)((const char*)sA + row * 128 + (ch << 4));
    }
#pragma unroll
    for (int f = 0; f < 4; f++) {
      int grp = f >> 1, fp = f & 1;
      int n = grp * 128 + wave * 32 + fp * 16 + l15;
      int ch = (ks * 4 + l4) ^ (n & 7);
      bf16x8 bv = *(const bf16x8*)((const char*)sW + n * 128 + (ch << 4));
#pragma unroll
      for (int m = 0; m < 4; m++)
        acc[m][f] = __builtin_amdgcn_mfma_f32_16x16x32_bf16(av[m], bv, acc[m][f], 0, 0, 0);
    }
  }
  // ---- epilogue: (lin+bl)*mask*sigm(gate+blg) -> Lbuf f32
#pragma unroll
  for (int fp = 0; fp < 2; fp++) {
    const int h = wave * 32 + fp * 16 + l15;
    const float blv = bl[h], blgv = blg[h];
#pragma unroll
    for (int m = 0; m < 4; m++) {
      f32x4 lin = acc[m][fp];
      f32x4 gat = acc[m][2 + fp];
#pragma unroll
      for (int r = 0; r < 4; r++) {
        const int g = g0 + m * 16 + l4 * 4 + r;
        const int i = g / 9, d = g - 9 * i;
        const int p = i + d - 4;
        const bool valid = (p >= 0) && (p < LL);
        const float mv = valid ? (float)smask[i] * (float)smask[valid ? p : 0] : 0.f;
        Lbuf[(size_t)g * HIDC + h] = (lin[r] + blv) * mv * sigm(gat[r] + blgv);
      }
    }
  }
}

// ---- kernel B: banded product + LN + gate + Wo projection, one chunk ----
// grid chunk*8 (block = (i = i0 + bid>>3, j-tile = bid&7)), 256 threads.
// og aliases d_out; each block reads only its own (i, j-tile) og rows and
// overwrites exactly those rows with the final output (ordered by barrier).
extern "C" __global__ void __launch_bounds__(256, 4)
kernB(const u16* __restrict__ ring, const u16* og,
      const float* __restrict__ Lbuf, const float* __restrict__ Wo,
      const float* __restrict__ osc, const float* __restrict__ obi,
      const float* __restrict__ bo, float* out, int k0, int i0)
{
  __shared__ u16 sWo[64 * 128];   // 16KB swizzled
  __shared__ u16 sA[64 * 128];    // 16KB swizzled
  __shared__ float sLb[9 * 128];
  const int bid = blockIdx.x;
  const int i = i0 + (bid >> 3), j0 = (bid & 7) * 64;
  const int t = threadIdx.x;
  const int lane = t & 63, wave = t >> 6;
  const int l15 = lane & 15, l4 = lane >> 4;
  { // stage Wo f32 -> swizzled bf16 (WoT[n=d][k], n<64, k<128)
    for (int idx = t; idx < 128 * 64; idx += 256) {
      int k = idx >> 6, d = idx & 63;
      sWo[d * 128 + (((k >> 3) ^ (d & 7)) << 3) + (k & 7)] = f2bf(Wo[idx]);
    }
    const float* lb = Lbuf + (size_t)i * (9 * HIDC);
    for (int idx = t; idx < 9 * HIDC; idx += 256) sLb[idx] = lb[idx];
  }
  __syncthreads();
  const int j = t >> 2, hq = t & 3, h0 = hq * 32;
  float acc[32];
#pragma unroll
  for (int e = 0; e < 32; e++) acc[e] = 0.f;
  for (int d = 0; d < 9; d++) {
    const int k = i + d - 4;
    if (k < 0 || k >= LL) continue;
    const int slot = k - k0;
    const u16* rp = ring + ((size_t)slot * LL + j0 + j) * HIDC + h0;
#pragma unroll
    for (int c4 = 0; c4 < 4; c4++) {
      uint4 rv = *(const uint4*)(rp + c4 * 8);
      const float4 lb0 = *(const float4*)(sLb + d * 128 + h0 + c4 * 8);
      const float4 lb1 = *(const float4*)(sLb + d * 128 + h0 + c4 * 8 + 4);
      acc[c4*8+0] = fmaf(lb0.x, bf2f(rv.x & 0xffff), acc[c4*8+0]);
      acc[c4*8+1] = fmaf(lb0.y, bf2f(rv.x >> 16),    acc[c4*8+1]);
      acc[c4*8+2] = fmaf(lb0.z, bf2f(rv.y & 0xffff), acc[c4*8+2]);
      acc[c4*8+3] = fmaf(lb0.w, bf2f(rv.y >> 16),    acc[c4*8+3]);
      acc[c4*8+4] = fmaf(lb1.x, bf2f(rv.z & 0xffff), acc[c4*8+4]);
      acc[c4*8+5] = fmaf(lb1.y, bf2f(rv.z >> 16),    acc[c4*8+5]);
      acc[c4*8+6] = fmaf(lb1.z, bf2f(rv.w & 0xffff), acc[c4*8+6]);
      acc[c4*8+7] = fmaf(lb1.w, bf2f(rv.w >> 16),    acc[c4*8+7]);
    }
  }
  // LN over 128 (4 threads per j)
  float s = 0.f, ss = 0.f;
#pragma unroll
  for (int e = 0; e < 32; e++) { s += acc[e]; ss += acc[e] * acc[e]; }
  s += __shfl_xor(s, 1); ss += __shfl_xor(ss, 1);
  s += __shfl_xor(s, 2); ss += __shfl_xor(ss, 2);
  const float mean = s * (1.f / 128.f);
  const float rstd = rsqrtf(ss * (1.f / 128.f) - mean * mean + 1e-6f);
  const u16* ogp = og + ((size_t)i * LL + j0 + j) * HIDC + h0;
  char* rowp = (char*)sA + j * 256;
#pragma unroll
  for (int c4 = 0; c4 < 4; c4++) {
    const float4 o0 = *(const float4*)(osc + h0 + c4 * 8);
    const float4 o1 = *(const float4*)(osc + h0 + c4 * 8 + 4);
    const float4 b0 = *(const float4*)(obi + h0 + c4 * 8);
    const float4 b1 = *(const float4*)(obi + h0 + c4 * 8 + 4);
    uint4 gv = *(const uint4*)(ogp + c4 * 8);
    float v0 = ((acc[c4*8+0] - mean) * rstd * o0.x + b0.x) * bf2f(gv.x & 0xffff);
    float v1 = ((acc[c4*8+1] - mean) * rstd * o0.y + b0.y) * bf2f(gv.x >> 16);
    float v2 = ((acc[c4*8+2] - mean) * rstd * o0.z + b0.z) * bf2f(gv.y & 0xffff);
    float v3 = ((acc[c4*8+3] - mean) * rstd * o0.w + b0.w) * bf2f(gv.y >> 16);
    float v4 = ((acc[c4*8+4] - mean) * rstd * o1.x + b1.x) * bf2f(gv.z & 0xffff);
    float v5 = ((acc[c4*8+5] - mean) * rstd * o1.y + b1.y) * bf2f(gv.z >> 16);
    float v6 = ((acc[c4*8+6] - mean) * rstd * o1.z + b1.z) * bf2f(gv.w & 0xffff);
    float v7 = ((acc[c4*8+7] - mean) * rstd * o1.w + b1.w) * bf2f(gv.w >> 16);
    uint4 pk;
    pk.x = (u32)f2bf(v0) | ((u32)f2bf(v1) << 16);
    pk.y = (u32)f2bf(v2) | ((u32)f2bf(v3) << 16);
    pk.z = (u32)f2bf(v4) | ((u32)f2bf(v5) << 16);
    pk.w = (u32)f2bf(v6) | ((u32)f2bf(v7) << 16);
    *(uint4*)(rowp + (((hq * 4 + c4) ^ (j & 7)) << 4)) = pk;
  }
  __syncthreads();   // og fully read; sA ready
  f32x4 acc2[4];
  f32x4 zero = {0.f, 0.f, 0.f, 0.f};
#pragma unroll
  for (int m = 0; m < 4; m++) acc2[m] = zero;
#pragma unroll
  for (int ks = 0; ks < 4; ks++) {
    int n = wave * 16 + l15;
    int chb = (ks * 4 + l4) ^ (n & 7);
    bf16x8 bv = *(const bf16x8*)((const char*)sWo + n * 256 + (chb << 4));
#pragma unroll
    for (int m = 0; m < 4; m++) {
      int row = m * 16 + l15;
      int cha = (ks * 4 + l4) ^ (row & 7);
      bf16x8 av = *(const bf16x8*)((const char*)sA + row * 256 + (cha << 4));
      acc2[m] = __builtin_amdgcn_mfma_f32_16x16x32_bf16(av, bv, acc2[m], 0, 0, 0);
    }
  }
  const int dim = wave * 16 + l15;
  const float bov = bo[dim];
#pragma unroll
  for (int m = 0; m < 4; m++) {
#pragma unroll
    for (int r = 0; r < 4; r++) {
      int jj = j0 + m * 16 + l4 * 4 + r;
      out[((size_t)i * LL + jj) * DIMC + dim] = acc2[m][r] + bov;
    }
  }
}

extern "C" void kernel_launch(void* const* d_in, const int* in_sizes, int n_in,
                              void* d_out, int out_size, void* d_ws, size_t ws_size,
                              hipStream_t stream) {
  const float* x    = (const float*)d_in[0];
  const int*   sm   = (const int*)d_in[1];
  const float* ns   = (const float*)d_in[2];
  const float* nb   = (const float*)d_in[3];
  const float* Wl   = (const float*)d_in[4];
  const float* bl   = (const float*)d_in[5];
  const float* Wr   = (const float*)d_in[6];
  const float* br   = (const float*)d_in[7];
  const float* Wlg  = (const float*)d_in[8];
  const float* blg  = (const float*)d_in[9];
  const float* Wrg  = (const float*)d_in[10];
  const float* brg  = (const float*)d_in[11];
  const float* Wog  = (const float*)d_in[12];
  const float* bog  = (const float*)d_in[13];
  const float* osc  = (const float*)d_in[14];
  const float* obi  = (const float*)d_in[15];
  const float* Wo   = (const float*)d_in[16];
  const float* bo   = (const float*)d_in[17];

  // ws layout: Lbuf f32 [4608*128] = 2,359,296 B, then right ring bf16.
  // CHUNK=256 -> total ~36.1 MB; fallback CHUNK=64 -> ~11.8 MB.
  const size_t LBUF_BYTES = (size_t)LL * 9 * HIDC * 4;
  char* ws = (char*)d_ws;
  float* Lbuf = (float*)ws;
  u16* ring = (u16*)(ws + LBUF_BYTES);

  int CHUNK = 256;
  if (ws_size < LBUF_BYTES + (size_t)(256 + 8) * LL * HIDC * 2) CHUNK = 64;
  u16* ogB = (u16*)d_out;   // og lives in d_out, chunk-local, consumed by kernB

  kernL<<<72, 256, 0, stream>>>(x, sm, ns, nb, Wl, bl, Wlg, blg, Lbuf);
  for (int i0 = 0; i0 < LL; i0 += CHUNK) {
    const int k0 = i0 - 4;
    kernA<<<CHUNK + 8, 256, 0, stream>>>(x, sm, ns, nb, Wr, br, Wrg, brg,
                                         Wog, bog, ring, ogB, k0, i0, CHUNK);
    kernB<<<CHUNK * 8, 256, 0, stream>>>(ring, ogB, Lbuf, Wo, osc, obi, bo,
                                         (float*)d_out, k0, i0);
  }
}

// Round 4
// 178.594 us; speedup vs baseline: 5.2615x; 1.2469x over previous
//
#include <hip/hip_runtime.h>

typedef unsigned short u16;
typedef unsigned int u32;

#define LL 512
#define DIMC 64
#define HIDC 128

typedef __attribute__((ext_vector_type(8))) __bf16 bf16x8;
typedef __attribute__((ext_vector_type(4))) float f32x4;

__device__ __forceinline__ u16 f2bf(float f) {
  u32 u = __float_as_uint(f);
  u = u + 0x7FFFu + ((u >> 16) & 1u);   // RNE
  return (u16)(u >> 16);
}
__device__ __forceinline__ float bf2f(u32 us) {
  return __uint_as_float(us << 16);
}
__device__ __forceinline__ float sigm(float x) {
  return 1.0f / (1.0f + __expf(-x));
}

// ---- prep: build swizzled bf16 LDS images of all weights, once ----------
// WTr rows n[0,384) = [Wr|Wrg|Wog], 64k each, 16B chunks at c^(n&7).
// WTl rows n[0,256) = [Wl|Wlg]. WoT rows d[0,64), 128k, chunk (k>>3)^(d&7).
extern "C" __global__ void prep(const float* __restrict__ Wr, const float* __restrict__ Wrg,
                                const float* __restrict__ Wog, const float* __restrict__ Wl,
                                const float* __restrict__ Wlg, const float* __restrict__ Wo,
                                u16* __restrict__ WTr, u16* __restrict__ WTl,
                                u16* __restrict__ WoT)
{
  int t = blockIdx.x * blockDim.x + threadIdx.x;
  int stride = gridDim.x * blockDim.x;
  for (int idx = t; idx < 384 * 64; idx += stride) {
    int n = idx >> 6, k = idx & 63;
    const float* W = (n < 128) ? Wr : (n < 256 ? Wrg : Wog);
    WTr[(n << 6) + (((k >> 3) ^ (n & 7)) << 3) + (k & 7)] = f2bf(W[k * HIDC + (n & 127)]);
  }
  for (int idx = t; idx < 256 * 64; idx += stride) {
    int n = idx >> 6, k = idx & 63;
    const float* W = (n < 128) ? Wl : Wlg;
    WTl[(n << 6) + (((k >> 3) ^ (n & 7)) << 3) + (k & 7)] = f2bf(W[k * HIDC + (n & 127)]);
  }
  for (int idx = t; idx < 64 * 128; idx += stride) {
    int d = idx >> 7, k = idx & 127;
    WoT[(d << 7) + (((k >> 3) ^ (d & 7)) << 3) + (k & 7)] = f2bf(Wo[k * DIMC + d]);
  }
}

// ---- kernel A: LN + right/og projections (MFMA), one chunk of rows ------
// grid (CHUNK+8)*4: block = (row p = k0 + bid>>2, quarter = bid&3 -> 2 q-tiles).
// 256 threads (4 waves). Round-3 was 264 blocks x 8 serial tiles: 10.7%
// occupancy, latency-bound (84us). Now 1056 blocks, trivial staging.
extern "C" __global__ void __launch_bounds__(256, 2)
kernA(const float* __restrict__ x, const int* __restrict__ smask,
      const float* __restrict__ ns, const float* __restrict__ nb,
      const float* __restrict__ br, const float* __restrict__ brg,
      const float* __restrict__ bog, const u16* __restrict__ WTr,
      u16* __restrict__ ring, u16* og, int k0, int i0, int chunk)
{
  __shared__ u16 sWT[384 * 64];   // 48KB, swizzled image (copied linearly)
  __shared__ u16 sA[64 * 64];     // 8KB, swizzled
  const int bid = blockIdx.x;
  const int slot = bid >> 2, quarter = bid & 3;
  const int p = k0 + slot;
  if (p < 0 || p >= LL) return;
  const bool store_og = (p >= i0) && (p < i0 + chunk);
  const int t = threadIdx.x;
  const int lane = t & 63;
  const int wave = t >> 6;
  const int l15 = lane & 15, l4 = lane >> 4;

  { // stage weights: linear uint4 copy of pre-swizzled image (conflict-free)
    const uint4* src = (const uint4*)WTr;
    uint4* dst = (uint4*)sWT;
#pragma unroll
    for (int c = 0; c < 12; ++c) dst[t + c * 256] = src[t + c * 256];
  }

  const float mrow = (float)smask[p];
  const int ql = t >> 2, qc = t & 3;      // pair-in-tile, dim-quarter
  float4 nsv[4], nbv[4];
#pragma unroll
  for (int j = 0; j < 4; j++) {
    nsv[j] = *(const float4*)(ns + qc * 16 + j * 4);
    nbv[j] = *(const float4*)(nb + qc * 16 + j * 4);
  }
  float brv[2], brgv[2], bogv[2];
#pragma unroll
  for (int fp = 0; fp < 2; fp++) {
    int h = wave * 32 + fp * 16 + l15;
    brv[fp] = br[h]; brgv[fp] = brg[h]; bogv[fp] = bog[h];
  }

  for (int tile = quarter * 2; tile < quarter * 2 + 2; ++tile) {
    const int q0 = tile * 64;
    { // ---- LN -> sA (bf16, swizzled)
      const int q = q0 + ql;
      const float* xp = x + ((size_t)p * LL + q) * DIMC + qc * 16;
      float4 xv[4];
      float s = 0.f, ss = 0.f;
#pragma unroll
      for (int j = 0; j < 4; j++) {
        xv[j] = *(const float4*)(xp + j * 4);
        s += xv[j].x + xv[j].y + xv[j].z + xv[j].w;
        ss += xv[j].x * xv[j].x + xv[j].y * xv[j].y + xv[j].z * xv[j].z + xv[j].w * xv[j].w;
      }
      s += __shfl_xor(s, 1); ss += __shfl_xor(ss, 1);
      s += __shfl_xor(s, 2); ss += __shfl_xor(ss, 2);
      const float mean = s * (1.f / 64.f);
      const float var = ss * (1.f / 64.f) - mean * mean;
      const float rstd = rsqrtf(var + 1e-6f);
      u16 xb[16];
#pragma unroll
      for (int j = 0; j < 4; j++) {
        xb[j*4+0] = f2bf((xv[j].x - mean) * rstd * nsv[j].x + nbv[j].x);
        xb[j*4+1] = f2bf((xv[j].y - mean) * rstd * nsv[j].y + nbv[j].y);
        xb[j*4+2] = f2bf((xv[j].z - mean) * rstd * nsv[j].z + nbv[j].z);
        xb[j*4+3] = f2bf((xv[j].w - mean) * rstd * nsv[j].w + nbv[j].w);
      }
      uint4 c0, c1;
      c0.x = (u32)xb[0]  | ((u32)xb[1]  << 16);
      c0.y = (u32)xb[2]  | ((u32)xb[3]  << 16);
      c0.z = (u32)xb[4]  | ((u32)xb[5]  << 16);
      c0.w = (u32)xb[6]  | ((u32)xb[7]  << 16);
      c1.x = (u32)xb[8]  | ((u32)xb[9]  << 16);
      c1.y = (u32)xb[10] | ((u32)xb[11] << 16);
      c1.z = (u32)xb[12] | ((u32)xb[13] << 16);
      c1.w = (u32)xb[14] | ((u32)xb[15] << 16);
      char* rowp = (char*)sA + ql * 128;
      *(uint4*)(rowp + (((qc * 2 + 0) ^ (ql & 7)) << 4)) = c0;
      *(uint4*)(rowp + (((qc * 2 + 1) ^ (ql & 7)) << 4)) = c1;
    }
    __syncthreads();
    // ---- MFMA: [64 pairs x 64k] @ [64k x 384n], wave owns 32 cols of each group
    f32x4 acc[4][6];
    f32x4 zero = {0.f, 0.f, 0.f, 0.f};
#pragma unroll
    for (int m = 0; m < 4; m++)
#pragma unroll
      for (int f = 0; f < 6; f++) acc[m][f] = zero;
#pragma unroll
    for (int ks = 0; ks < 2; ks++) {
      bf16x8 av[4];
#pragma unroll
      for (int m = 0; m < 4; m++) {
        int row = m * 16 + l15;
        int ch = (ks * 4 + l4) ^ (row & 7);
        av[m] = *(const bf16x8*)((const char*)sA + row * 128 + (ch << 4));
      }
#pragma unroll
      for (int f = 0; f < 6; f++) {
        int g = f >> 1, fp = f & 1;
        int n = g * 128 + wave * 32 + fp * 16 + l15;
        int ch = (ks * 4 + l4) ^ (n & 7);
        bf16x8 bv = *(const bf16x8*)((const char*)sWT + n * 128 + (ch << 4));
#pragma unroll
        for (int m = 0; m < 4; m++)
          acc[m][f] = __builtin_amdgcn_mfma_f32_16x16x32_bf16(av[m], bv, acc[m][f], 0, 0, 0);
      }
    }
    __syncthreads();   // all LDS reads done before next tile's LN writes
    // ---- epilogue: bias, mask, sigmoid gates; store right(ring)/og bf16
#pragma unroll
    for (int m = 0; m < 4; m++) {
      float mv[4];
#pragma unroll
      for (int r = 0; r < 4; r++)
        mv[r] = mrow * (float)smask[q0 + m * 16 + l4 * 4 + r];
#pragma unroll
      for (int fp = 0; fp < 2; fp++) {
        const int h = wave * 32 + fp * 16 + l15;
        f32x4 lin = acc[m][fp];
        f32x4 gat = acc[m][2 + fp];
        f32x4 ogv = acc[m][4 + fp];
#pragma unroll
        for (int r = 0; r < 4; r++) {
          int qq = q0 + m * 16 + l4 * 4 + r;
          float rv = (lin[r] + brv[fp]) * mv[r] * sigm(gat[r] + brgv[fp]);
          ring[((size_t)slot * LL + qq) * HIDC + h] = f2bf(rv);
          if (store_og) {
            float ov = sigm(ogv[r] + bogv[fp]);
            og[((size_t)p * LL + qq) * HIDC + h] = f2bf(ov);
          }
        }
      }
    }
  }
}

// ---- kernel L: left on the 9 diagonals via MFMA -------------------------
// Flattened row space g = i*9 + d, M = 4608. GEMM [4608 x 64] @ [64 x 256].
// grid 72 blocks x 256 threads, 64 rows per block.
extern "C" __global__ void __launch_bounds__(256, 2)
kernL(const float* __restrict__ x, const int* __restrict__ smask,
      const float* __restrict__ ns, const float* __restrict__ nb,
      const float* __restrict__ bl, const float* __restrict__ blg,
      const u16* __restrict__ WTl, float* __restrict__ Lbuf)
{
  __shared__ u16 sW[256 * 64];    // 32KB swizzled image
  __shared__ u16 sA[64 * 64];     // 8KB swizzled LN'd rows
  const int g0 = blockIdx.x * 64;
  const int t = threadIdx.x;
  const int lane = t & 63, wave = t >> 6;
  const int l15 = lane & 15, l4 = lane >> 4;

  { // stage weights: linear uint4 copy of pre-swizzled image
    const uint4* src = (const uint4*)WTl;
    uint4* dst = (uint4*)sW;
#pragma unroll
    for (int c = 0; c < 8; ++c) dst[t + c * 256] = src[t + c * 256];
  }

  const int ql = t >> 2, qc = t & 3;     // row-in-tile, dim-quarter
  { // ---- LN -> sA: row g = g0+ql -> (i = g/9, d = g%9, p = i+d-4)
    const int g = g0 + ql;
    const int i = g / 9, d = g - 9 * i;
    int p = i + d - 4;
    p = (p < 0) ? 0 : (p > LL - 1 ? LL - 1 : p);   // clamp; invalid rows zeroed later
    const float* xp = x + ((size_t)p * LL + i) * DIMC + qc * 16;
    float4 xv[4];
    float s = 0.f, ss = 0.f;
#pragma unroll
    for (int j = 0; j < 4; j++) {
      xv[j] = *(const float4*)(xp + j * 4);
      s += xv[j].x + xv[j].y + xv[j].z + xv[j].w;
      ss += xv[j].x * xv[j].x + xv[j].y * xv[j].y + xv[j].z * xv[j].z + xv[j].w * xv[j].w;
    }
    s += __shfl_xor(s, 1); ss += __shfl_xor(ss, 1);
    s += __shfl_xor(s, 2); ss += __shfl_xor(ss, 2);
    const float mean = s * (1.f / 64.f);
    const float rstd = rsqrtf(ss * (1.f / 64.f) - mean * mean + 1e-6f);
    u16 xb[16];
#pragma unroll
    for (int j = 0; j < 4; j++) {
      const float4 nsv = *(const float4*)(ns + qc * 16 + j * 4);
      const float4 nbv = *(const float4*)(nb + qc * 16 + j * 4);
      xb[j*4+0] = f2bf((xv[j].x - mean) * rstd * nsv.x + nbv.x);
      xb[j*4+1] = f2bf((xv[j].y - mean) * rstd * nsv.y + nbv.y);
      xb[j*4+2] = f2bf((xv[j].z - mean) * rstd * nsv.z + nbv.z);
      xb[j*4+3] = f2bf((xv[j].w - mean) * rstd * nsv.w + nbv.w);
    }
    uint4 c0, c1;
    c0.x = (u32)xb[0]  | ((u32)xb[1]  << 16);
    c0.y = (u32)xb[2]  | ((u32)xb[3]  << 16);
    c0.z = (u32)xb[4]  | ((u32)xb[5]  << 16);
    c0.w = (u32)xb[6]  | ((u32)xb[7]  << 16);
    c1.x = (u32)xb[8]  | ((u32)xb[9]  << 16);
    c1.y = (u32)xb[10] | ((u32)xb[11] << 16);
    c1.z = (u32)xb[12] | ((u32)xb[13] << 16);
    c1.w = (u32)xb[14] | ((u32)xb[15] << 16);
    char* rowp = (char*)sA + ql * 128;
    *(uint4*)(rowp + (((qc * 2 + 0) ^ (ql & 7)) << 4)) = c0;
    *(uint4*)(rowp + (((qc * 2 + 1) ^ (ql & 7)) << 4)) = c1;
  }
  __syncthreads();
  // ---- MFMA: [64 rows x 64k] @ [64k x 256n]
  f32x4 acc[4][4];
  f32x4 zero = {0.f, 0.f, 0.f, 0.f};
#pragma unroll
  for (int m = 0; m < 4; m++)
#pragma unroll
    for (int f = 0; f < 4; f++) acc[m][f] = zero;
#pragma unroll
  for (int ks = 0; ks < 2; ks++) {
    bf16x8 av[4];
#pragma unroll
    for (int m = 0; m < 4; m++) {
      int row = m * 16 + l15;
      int ch = (ks * 4 + l4) ^ (row & 7);
      av[m] = *(const bf16x8*)((const char*)sA + row * 128 + (ch << 4));
    }
#pragma unroll
    for (int f = 0; f < 4; f++) {
      int grp = f >> 1, fp = f & 1;
      int n = grp * 128 + wave * 32 + fp * 16 + l15;
      int ch = (ks * 4 + l4) ^ (n & 7);
      bf16x8 bv = *(const bf16x8*)((const char*)sW + n * 128 + (ch << 4));
#pragma unroll
      for (int m = 0; m < 4; m++)
        acc[m][f] = __builtin_amdgcn_mfma_f32_16x16x32_bf16(av[m], bv, acc[m][f], 0, 0, 0);
    }
  }
  // ---- epilogue: (lin+bl)*mask*sigm(gate+blg) -> Lbuf f32
#pragma unroll
  for (int fp = 0; fp < 2; fp++) {
    const int h = wave * 32 + fp * 16 + l15;
    const float blv = bl[h], blgv = blg[h];
#pragma unroll
    for (int m = 0; m < 4; m++) {
      f32x4 lin = acc[m][fp];
      f32x4 gat = acc[m][2 + fp];
#pragma unroll
      for (int r = 0; r < 4; r++) {
        const int g = g0 + m * 16 + l4 * 4 + r;
        const int i = g / 9, d = g - 9 * i;
        const int p = i + d - 4;
        const bool valid = (p >= 0) && (p < LL);
        const float mv = valid ? (float)smask[i] * (float)smask[valid ? p : 0] : 0.f;
        Lbuf[(size_t)g * HIDC + h] = (lin[r] + blv) * mv * sigm(gat[r] + blgv);
      }
    }
  }
}

// ---- kernel B: banded product + LN + gate + Wo projection, one chunk ----
// grid chunk*8 (block = (i = i0 + bid>>3, j-tile = bid&7)), 256 threads.
// og aliases d_out; each block reads only its own (i, j-tile) og rows and
// overwrites exactly those rows with the final output (ordered by barrier).
extern "C" __global__ void __launch_bounds__(256, 4)
kernB(const u16* __restrict__ ring, const u16* og,
      const float* __restrict__ Lbuf, const u16* __restrict__ WoT,
      const float* __restrict__ osc, const float* __restrict__ obi,
      const float* __restrict__ bo, float* out, int k0, int i0)
{
  __shared__ u16 sWo[64 * 128];   // 16KB swizzled image
  __shared__ u16 sA[64 * 128];    // 16KB swizzled
  __shared__ float sLb[9 * 128];
  const int bid = blockIdx.x;
  const int i = i0 + (bid >> 3), j0 = (bid & 7) * 64;
  const int t = threadIdx.x;
  const int lane = t & 63, wave = t >> 6;
  const int l15 = lane & 15, l4 = lane >> 4;
  { // stage Wo: linear uint4 copy of pre-swizzled image
    const uint4* src = (const uint4*)WoT;
    uint4* dst = (uint4*)sWo;
#pragma unroll
    for (int c = 0; c < 4; ++c) dst[t + c * 256] = src[t + c * 256];
    const float* lb = Lbuf + (size_t)i * (9 * HIDC);
    for (int idx = t; idx < 9 * HIDC; idx += 256) sLb[idx] = lb[idx];
  }
  __syncthreads();
  const int j = t >> 2, hq = t & 3, h0 = hq * 32;
  float acc[32];
#pragma unroll
  for (int e = 0; e < 32; e++) acc[e] = 0.f;
  for (int d = 0; d < 9; d++) {
    const int k = i + d - 4;
    if (k < 0 || k >= LL) continue;
    const int slot = k - k0;
    const u16* rp = ring + ((size_t)slot * LL + j0 + j) * HIDC + h0;
#pragma unroll
    for (int c4 = 0; c4 < 4; c4++) {
      uint4 rv = *(const uint4*)(rp + c4 * 8);
      const float4 lb0 = *(const float4*)(sLb + d * 128 + h0 + c4 * 8);
      const float4 lb1 = *(const float4*)(sLb + d * 128 + h0 + c4 * 8 + 4);
      acc[c4*8+0] = fmaf(lb0.x, bf2f(rv.x & 0xffff), acc[c4*8+0]);
      acc[c4*8+1] = fmaf(lb0.y, bf2f(rv.x >> 16),    acc[c4*8+1]);
      acc[c4*8+2] = fmaf(lb0.z, bf2f(rv.y & 0xffff), acc[c4*8+2]);
      acc[c4*8+3] = fmaf(lb0.w, bf2f(rv.y >> 16),    acc[c4*8+3]);
      acc[c4*8+4] = fmaf(lb1.x, bf2f(rv.z & 0xffff), acc[c4*8+4]);
      acc[c4*8+5] = fmaf(lb1.y, bf2f(rv.z >> 16),    acc[c4*8+5]);
      acc[c4*8+6] = fmaf(lb1.z, bf2f(rv.w & 0xffff), acc[c4*8+6]);
      acc[c4*8+7] = fmaf(lb1.w, bf2f(rv.w >> 16),    acc[c4*8+7]);
    }
  }
  // LN over 128 (4 threads per j)
  float s = 0.f, ss = 0.f;
#pragma unroll
  for (int e = 0; e < 32; e++) { s += acc[e]; ss += acc[e] * acc[e]; }
  s += __shfl_xor(s, 1); ss += __shfl_xor(ss, 1);
  s += __shfl_xor(s, 2); ss += __shfl_xor(ss, 2);
  const float mean = s * (1.f / 128.f);
  const float rstd = rsqrtf(ss * (1.f / 128.f) - mean * mean + 1e-6f);
  const u16* ogp = og + ((size_t)i * LL + j0 + j) * HIDC + h0;
  char* rowp = (char*)sA + j * 256;
#pragma unroll
  for (int c4 = 0; c4 < 4; c4++) {
    const float4 o0 = *(const float4*)(osc + h0 + c4 * 8);
    const float4 o1 = *(const float4*)(osc + h0 + c4 * 8 + 4);
    const float4 b0 = *(const float4*)(obi + h0 + c4 * 8);
    const float4 b1 = *(const float4*)(obi + h0 + c4 * 8 + 4);
    uint4 gv = *(const uint4*)(ogp + c4 * 8);
    float v0 = ((acc[c4*8+0] - mean) * rstd * o0.x + b0.x) * bf2f(gv.x & 0xffff);
    float v1 = ((acc[c4*8+1] - mean) * rstd * o0.y + b0.y) * bf2f(gv.x >> 16);
    float v2 = ((acc[c4*8+2] - mean) * rstd * o0.z + b0.z) * bf2f(gv.y & 0xffff);
    float v3 = ((acc[c4*8+3] - mean) * rstd * o0.w + b0.w) * bf2f(gv.y >> 16);
    float v4 = ((acc[c4*8+4] - mean) * rstd * o1.x + b1.x) * bf2f(gv.z & 0xffff);
    float v5 = ((acc[c4*8+5] - mean) * rstd * o1.y + b1.y) * bf2f(gv.z >> 16);
    float v6 = ((acc[c4*8+6] - mean) * rstd * o1.z + b1.z) * bf2f(gv.w & 0xffff);
    float v7 = ((acc[c4*8+7] - mean) * rstd * o1.w + b1.w) * bf2f(gv.w >> 16);
    uint4 pk;
    pk.x = (u32)f2bf(v0) | ((u32)f2bf(v1) << 16);
    pk.y = (u32)f2bf(v2) | ((u32)f2bf(v3) << 16);
    pk.z = (u32)f2bf(v4) | ((u32)f2bf(v5) << 16);
    pk.w = (u32)f2bf(v6) | ((u32)f2bf(v7) << 16);
    *(uint4*)(rowp + (((hq * 4 + c4) ^ (j & 7)) << 4)) = pk;
  }
  __syncthreads();   // og fully read; sA ready
  f32x4 acc2[4];
  f32x4 zero = {0.f, 0.f, 0.f, 0.f};
#pragma unroll
  for (int m = 0; m < 4; m++) acc2[m] = zero;
#pragma unroll
  for (int ks = 0; ks < 4; ks++) {
    int n = wave * 16 + l15;
    int chb = (ks * 4 + l4) ^ (n & 7);
    bf16x8 bv = *(const bf16x8*)((const char*)sWo + n * 256 + (chb << 4));
#pragma unroll
    for (int m = 0; m < 4; m++) {
      int row = m * 16 + l15;
      int cha = (ks * 4 + l4) ^ (row & 7);
      bf16x8 av = *(const bf16x8*)((const char*)sA + row * 256 + (cha << 4));
      acc2[m] = __builtin_amdgcn_mfma_f32_16x16x32_bf16(av, bv, acc2[m], 0, 0, 0);
    }
  }
  const int dim = wave * 16 + l15;
  const float bov = bo[dim];
#pragma unroll
  for (int m = 0; m < 4; m++) {
#pragma unroll
    for (int r = 0; r < 4; r++) {
      int jj = j0 + m * 16 + l4 * 4 + r;
      out[((size_t)i * LL + jj) * DIMC + dim] = acc2[m][r] + bov;
    }
  }
}

extern "C" void kernel_launch(void* const* d_in, const int* in_sizes, int n_in,
                              void* d_out, int out_size, void* d_ws, size_t ws_size,
                              hipStream_t stream) {
  const float* x    = (const float*)d_in[0];
  const int*   sm   = (const int*)d_in[1];
  const float* ns   = (const float*)d_in[2];
  const float* nb   = (const float*)d_in[3];
  const float* Wl   = (const float*)d_in[4];
  const float* bl   = (const float*)d_in[5];
  const float* Wr   = (const float*)d_in[6];
  const float* br   = (const float*)d_in[7];
  const float* Wlg  = (const float*)d_in[8];
  const float* blg  = (const float*)d_in[9];
  const float* Wrg  = (const float*)d_in[10];
  const float* brg  = (const float*)d_in[11];
  const float* Wog  = (const float*)d_in[12];
  const float* bog  = (const float*)d_in[13];
  const float* osc  = (const float*)d_in[14];
  const float* obi  = (const float*)d_in[15];
  const float* Wo   = (const float*)d_in[16];
  const float* bo   = (const float*)d_in[17];

  // ws layout: Lbuf f32 [4608*128] | WTr 48KB | WTl 32KB | WoT 16KB | ring.
  // CHUNK=256 -> total ~37.1 MB; fallback CHUNK=64 -> ~12.3 MB.
  const size_t LBUF_BYTES = (size_t)LL * 9 * HIDC * 4;   // 2,359,296
  char* ws = (char*)d_ws;
  float* Lbuf = (float*)ws;
  u16* WTr = (u16*)(ws + LBUF_BYTES);
  u16* WTl = (u16*)(ws + LBUF_BYTES + 49152);
  u16* WoT = (u16*)(ws + LBUF_BYTES + 49152 + 32768);
  u16* ring = (u16*)(ws + LBUF_BYTES + 49152 + 32768 + 16384);

  int CHUNK = 256;
  if (ws_size < LBUF_BYTES + 98304 + (size_t)(256 + 8) * LL * HIDC * 2) CHUNK = 64;
  u16* ogB = (u16*)d_out;   // og lives in d_out, chunk-local, consumed by kernB

  prep<<<32, 256, 0, stream>>>(Wr, Wrg, Wog, Wl, Wlg, Wo, WTr, WTl, WoT);
  kernL<<<72, 256, 0, stream>>>(x, sm, ns, nb, bl, blg, WTl, Lbuf);
  for (int i0 = 0; i0 < LL; i0 += CHUNK) {
    const int k0 = i0 - 4;
    kernA<<<(CHUNK + 8) * 4, 256, 0, stream>>>(x, sm, ns, nb, br, brg, bog,
                                               WTr, ring, ogB, k0, i0, CHUNK);
    kernB<<<CHUNK * 8, 256, 0, stream>>>(ring, ogB, Lbuf, WoT, osc, obi, bo,
                                         (float*)d_out, k0, i0);
  }
}

// Round 8
// 175.704 us; speedup vs baseline: 5.3480x; 1.0165x over previous
//
#include <hip/hip_runtime.h>

typedef unsigned short u16;
typedef unsigned int u32;

#define LL 512
#define DIMC 64
#define HIDC 128

typedef __attribute__((ext_vector_type(8))) __bf16 bf16x8;
typedef __attribute__((ext_vector_type(4))) float f32x4;

__device__ __forceinline__ u16 f2bf(float f) {
  u32 u = __float_as_uint(f);
  u = u + 0x7FFFu + ((u >> 16) & 1u);   // RNE
  return (u16)(u >> 16);
}
__device__ __forceinline__ float bf2f(u32 us) {
  return __uint_as_float(us << 16);
}
__device__ __forceinline__ float sigm(float x) {
  return 1.0f / (1.0f + __expf(-x));
}

// ---- prep: build swizzled bf16 LDS images of all weights (round-4) -----
// WTr rows n[0,384) = [Wr|Wrg|Wog]. WTl rows n[0,256) = [Wl|Wlg].
// WoT rows d[0,64). NOTE: the reg-B-frag path (linear images consumed as
// VGPR fragments) fails correctness (r5/r6/r7 bisection, absmax 1.4-1.7e-2
// vs 3.9e-3) for reasons static analysis can't see — ALL MFMA B operands
// must route through these swizzled images + LDS.
extern "C" __global__ void prep(const float* __restrict__ Wr, const float* __restrict__ Wrg,
                                const float* __restrict__ Wog, const float* __restrict__ Wl,
                                const float* __restrict__ Wlg, const float* __restrict__ Wo,
                                u16* __restrict__ WTr, u16* __restrict__ WTl,
                                u16* __restrict__ WoT)
{
  int t = blockIdx.x * blockDim.x + threadIdx.x;
  int stride = gridDim.x * blockDim.x;
  for (int idx = t; idx < 384 * 64; idx += stride) {
    int n = idx >> 6, k = idx & 63;
    const float* W = (n < 128) ? Wr : (n < 256 ? Wrg : Wog);
    WTr[(n << 6) + (((k >> 3) ^ (n & 7)) << 3) + (k & 7)] = f2bf(W[k * HIDC + (n & 127)]);
  }
  for (int idx = t; idx < 256 * 64; idx += stride) {
    int n = idx >> 6, k = idx & 63;
    const float* W = (n < 128) ? Wl : Wlg;
    WTl[(n << 6) + (((k >> 3) ^ (n & 7)) << 3) + (k & 7)] = f2bf(W[k * HIDC + (n & 127)]);
  }
  for (int idx = t; idx < 64 * 128; idx += stride) {
    int d = idx >> 7, k = idx & 127;
    WoT[(d << 7) + (((k >> 3) ^ (d & 7)) << 3) + (k & 7)] = f2bf(Wo[k * DIMC + d]);
  }
}

// ---- kernel A: LN + right/og projections (round-4 math, restructured) ---
// grid (CHUNK+8)*8: block = (row p = k0 + bid>>3, q-tile = bid&7).
// B-path: round-4 verified (48KB swizzled sWT copy + swizzled reads).
// Value-identical changes vs round-4: 1 tile/block; ring AND og stores
// bounced through padded LDS plane -> 4+4 dwordx4 per thread.
extern "C" __global__ void __launch_bounds__(256, 2)
kernA(const float* __restrict__ x, const int* __restrict__ smask,
      const float* __restrict__ ns, const float* __restrict__ nb,
      const float* __restrict__ br, const float* __restrict__ brg,
      const float* __restrict__ bog, const u16* __restrict__ WTr,
      u16* __restrict__ ring, u16* og, int k0, int i0, int chunk)
{
  __shared__ u16 sWT[384 * 64];   // 48KB, swizzled image (copied linearly)
  __shared__ u16 sA[64 * 64];     // 8KB, swizzled
  __shared__ u16 sR[64 * 136];    // 17KB padded bounce plane
  const int bid = blockIdx.x;
  const int slot = bid >> 3, tile = bid & 7;
  const int p = k0 + slot;
  if (p < 0 || p >= LL) return;
  const bool store_og = (p >= i0) && (p < i0 + chunk);
  const int t = threadIdx.x;
  const int lane = t & 63;
  const int wave = t >> 6;
  const int l15 = lane & 15, l4 = lane >> 4;
  const int q0 = tile * 64;

  { // stage weights: linear uint4 copy of pre-swizzled image (conflict-free)
    const uint4* src = (const uint4*)WTr;
    uint4* dst = (uint4*)sWT;
#pragma unroll
    for (int c = 0; c < 12; ++c) dst[t + c * 256] = src[t + c * 256];
  }

  const float mrow = (float)smask[p];
  const int ql = t >> 2, qc = t & 3;      // pair-in-tile, dim-quarter
  float4 nsv[4], nbv[4];
#pragma unroll
  for (int j = 0; j < 4; j++) {
    nsv[j] = *(const float4*)(ns + qc * 16 + j * 4);
    nbv[j] = *(const float4*)(nb + qc * 16 + j * 4);
  }
  float brv[2], brgv[2], bogv[2];
#pragma unroll
  for (int fp = 0; fp < 2; fp++) {
    int h = wave * 32 + fp * 16 + l15;
    brv[fp] = br[h]; brgv[fp] = brg[h]; bogv[fp] = bog[h];
  }

  { // ---- LN -> sA (bf16, swizzled) — round-4 verbatim
    const int q = q0 + ql;
    const float* xp = x + ((size_t)p * LL + q) * DIMC + qc * 16;
    float4 xv[4];
    float s = 0.f, ss = 0.f;
#pragma unroll
    for (int j = 0; j < 4; j++) {
      xv[j] = *(const float4*)(xp + j * 4);
      s += xv[j].x + xv[j].y + xv[j].z + xv[j].w;
      ss += xv[j].x * xv[j].x + xv[j].y * xv[j].y + xv[j].z * xv[j].z + xv[j].w * xv[j].w;
    }
    s += __shfl_xor(s, 1); ss += __shfl_xor(ss, 1);
    s += __shfl_xor(s, 2); ss += __shfl_xor(ss, 2);
    const float mean = s * (1.f / 64.f);
    const float var = ss * (1.f / 64.f) - mean * mean;
    const float rstd = rsqrtf(var + 1e-6f);
    u16 xb[16];
#pragma unroll
    for (int j = 0; j < 4; j++) {
      xb[j*4+0] = f2bf((xv[j].x - mean) * rstd * nsv[j].x + nbv[j].x);
      xb[j*4+1] = f2bf((xv[j].y - mean) * rstd * nsv[j].y + nbv[j].y);
      xb[j*4+2] = f2bf((xv[j].z - mean) * rstd * nsv[j].z + nbv[j].z);
      xb[j*4+3] = f2bf((xv[j].w - mean) * rstd * nsv[j].w + nbv[j].w);
    }
    uint4 c0, c1;
    c0.x = (u32)xb[0]  | ((u32)xb[1]  << 16);
    c0.y = (u32)xb[2]  | ((u32)xb[3]  << 16);
    c0.z = (u32)xb[4]  | ((u32)xb[5]  << 16);
    c0.w = (u32)xb[6]  | ((u32)xb[7]  << 16);
    c1.x = (u32)xb[8]  | ((u32)xb[9]  << 16);
    c1.y = (u32)xb[10] | ((u32)xb[11] << 16);
    c1.z = (u32)xb[12] | ((u32)xb[13] << 16);
    c1.w = (u32)xb[14] | ((u32)xb[15] << 16);
    char* rowp = (char*)sA + ql * 128;
    *(uint4*)(rowp + (((qc * 2 + 0) ^ (ql & 7)) << 4)) = c0;
    *(uint4*)(rowp + (((qc * 2 + 1) ^ (ql & 7)) << 4)) = c1;
  }
  __syncthreads();
  // ---- MFMA: [64 pairs x 64k] @ [64k x 384n] — round-4 verbatim
  f32x4 acc[4][6];
  f32x4 zero = {0.f, 0.f, 0.f, 0.f};
#pragma unroll
  for (int m = 0; m < 4; m++)
#pragma unroll
    for (int f = 0; f < 6; f++) acc[m][f] = zero;
#pragma unroll
  for (int ks = 0; ks < 2; ks++) {
    bf16x8 av[4];
#pragma unroll
    for (int m = 0; m < 4; m++) {
      int row = m * 16 + l15;
      int ch = (ks * 4 + l4) ^ (row & 7);
      av[m] = *(const bf16x8*)((const char*)sA + row * 128 + (ch << 4));
    }
#pragma unroll
    for (int f = 0; f < 6; f++) {
      int g = f >> 1, fp = f & 1;
      int n = g * 128 + wave * 32 + fp * 16 + l15;
      int ch = (ks * 4 + l4) ^ (n & 7);
      bf16x8 bv = *(const bf16x8*)((const char*)sWT + n * 128 + (ch << 4));
#pragma unroll
      for (int m = 0; m < 4; m++)
        acc[m][f] = __builtin_amdgcn_mfma_f32_16x16x32_bf16(av[m], bv, acc[m][f], 0, 0, 0);
    }
  }
  // ---- epilogue pass 1: ring values -> sR (same f2bf values as round-4)
  float mv[4];
#pragma unroll
  for (int r = 0; r < 4; r++)
    mv[r] = mrow;   // row mask filled below per m
#pragma unroll
  for (int m = 0; m < 4; m++) {
    float mvr[4];
#pragma unroll
    for (int r = 0; r < 4; r++)
      mvr[r] = mrow * (float)smask[q0 + m * 16 + l4 * 4 + r];
#pragma unroll
    for (int fp = 0; fp < 2; fp++) {
      const int h = wave * 32 + fp * 16 + l15;
      f32x4 lin = acc[m][fp];
      f32x4 gat = acc[m][2 + fp];
#pragma unroll
      for (int r = 0; r < 4; r++) {
        const int row = m * 16 + l4 * 4 + r;
        sR[row * 136 + h] = f2bf((lin[r] + brv[fp]) * mvr[r] * sigm(gat[r] + brgv[fp]));
      }
    }
  }
  __syncthreads();
  { // bounce sR -> ring (coalesced dwordx4)
    uint4* dst = (uint4*)(ring + ((size_t)slot * LL + q0) * HIDC);
#pragma unroll
    for (int c = 0; c < 4; c++) {
      const int g = t + c * 256;
      dst[g] = *(const uint4*)(sR + (g >> 4) * 136 + (g & 15) * 8);
    }
  }
  if (store_og) {   // block-uniform branch
    __syncthreads();  // ring bounce reads done before sR overwrite
    // ---- epilogue pass 2: og values -> sR
#pragma unroll
    for (int m = 0; m < 4; m++)
#pragma unroll
      for (int fp = 0; fp < 2; fp++) {
        const int h = wave * 32 + fp * 16 + l15;
        f32x4 ogv = acc[m][4 + fp];
#pragma unroll
        for (int r = 0; r < 4; r++) {
          const int row = m * 16 + l4 * 4 + r;
          sR[row * 136 + h] = f2bf(sigm(ogv[r] + bogv[fp]));
        }
      }
    __syncthreads();
    uint4* dst = (uint4*)(og + ((size_t)p * LL + q0) * HIDC);
#pragma unroll
    for (int c = 0; c < 4; c++) {
      const int g = t + c * 256;
      dst[g] = *(const uint4*)(sR + (g >> 4) * 136 + (g & 15) * 8);
    }
  }
}

// ---- kernel L: left on the 9 diagonals via MFMA (round-4, unchanged) ----
extern "C" __global__ void __launch_bounds__(256, 2)
kernL(const float* __restrict__ x, const int* __restrict__ smask,
      const float* __restrict__ ns, const float* __restrict__ nb,
      const float* __restrict__ bl, const float* __restrict__ blg,
      const u16* __restrict__ WTl, float* __restrict__ Lbuf)
{
  __shared__ u16 sW[256 * 64];    // 32KB swizzled image
  __shared__ u16 sA[64 * 64];     // 8KB swizzled LN'd rows
  const int g0 = blockIdx.x * 64;
  const int t = threadIdx.x;
  const int lane = t & 63, wave = t >> 6;
  const int l15 = lane & 15, l4 = lane >> 4;

  { // stage weights: linear uint4 copy of pre-swizzled image
    const uint4* src = (const uint4*)WTl;
    uint4* dst = (uint4*)sW;
#pragma unroll
    for (int c = 0; c < 8; ++c) dst[t + c * 256] = src[t + c * 256];
  }

  const int ql = t >> 2, qc = t & 3;     // row-in-tile, dim-quarter
  { // ---- LN -> sA: row g = g0+ql -> (i = g/9, d = g%9, p = i+d-4)
    const int g = g0 + ql;
    const int i = g / 9, d = g - 9 * i;
    int p = i + d - 4;
    p = (p < 0) ? 0 : (p > LL - 1 ? LL - 1 : p);   // clamp; invalid rows zeroed later
    const float* xp = x + ((size_t)p * LL + i) * DIMC + qc * 16;
    float4 xv[4];
    float s = 0.f, ss = 0.f;
#pragma unroll
    for (int j = 0; j < 4; j++) {
      xv[j] = *(const float4*)(xp + j * 4);
      s += xv[j].x + xv[j].y + xv[j].z + xv[j].w;
      ss += xv[j].x * xv[j].x + xv[j].y * xv[j].y + xv[j].z * xv[j].z + xv[j].w * xv[j].w;
    }
    s += __shfl_xor(s, 1); ss += __shfl_xor(ss, 1);
    s += __shfl_xor(s, 2); ss += __shfl_xor(ss, 2);
    const float mean = s * (1.f / 64.f);
    const float rstd = rsqrtf(ss * (1.f / 64.f) - mean * mean + 1e-6f);
    u16 xb[16];
#pragma unroll
    for (int j = 0; j < 4; j++) {
      const float4 nsv = *(const float4*)(ns + qc * 16 + j * 4);
      const float4 nbv = *(const float4*)(nb + qc * 16 + j * 4);
      xb[j*4+0] = f2bf((xv[j].x - mean) * rstd * nsv.x + nbv.x);
      xb[j*4+1] = f2bf((xv[j].y - mean) * rstd * nsv.y + nbv.y);
      xb[j*4+2] = f2bf((xv[j].z - mean) * rstd * nsv.z + nbv.z);
      xb[j*4+3] = f2bf((xv[j].w - mean) * rstd * nsv.w + nbv.w);
    }
    uint4 c0, c1;
    c0.x = (u32)xb[0]  | ((u32)xb[1]  << 16);
    c0.y = (u32)xb[2]  | ((u32)xb[3]  << 16);
    c0.z = (u32)xb[4]  | ((u32)xb[5]  << 16);
    c0.w = (u32)xb[6]  | ((u32)xb[7]  << 16);
    c1.x = (u32)xb[8]  | ((u32)xb[9]  << 16);
    c1.y = (u32)xb[10] | ((u32)xb[11] << 16);
    c1.z = (u32)xb[12] | ((u32)xb[13] << 16);
    c1.w = (u32)xb[14] | ((u32)xb[15] << 16);
    char* rowp = (char*)sA + ql * 128;
    *(uint4*)(rowp + (((qc * 2 + 0) ^ (ql & 7)) << 4)) = c0;
    *(uint4*)(rowp + (((qc * 2 + 1) ^ (ql & 7)) << 4)) = c1;
  }
  __syncthreads();
  // ---- MFMA: [64 rows x 64k] @ [64k x 256n]
  f32x4 acc[4][4];
  f32x4 zero = {0.f, 0.f, 0.f, 0.f};
#pragma unroll
  for (int m = 0; m < 4; m++)
#pragma unroll
    for (int f = 0; f < 4; f++) acc[m][f] = zero;
#pragma unroll
  for (int ks = 0; ks < 2; ks++) {
    bf16x8 av[4];
#pragma unroll
    for (int m = 0; m < 4; m++) {
      int row = m * 16 + l15;
      int ch = (ks * 4 + l4) ^ (row & 7);
      av[m] = *(const bf16x8*)((const char*)sA + row * 128 + (ch << 4));
    }
#pragma unroll
    for (int f = 0; f < 4; f++) {
      int grp = f >> 1, fp = f & 1;
      int n = grp * 128 + wave * 32 + fp * 16 + l15;
      int ch = (ks * 4 + l4) ^ (n & 7);
      bf16x8 bv = *(const bf16x8*)((const char*)sW + n * 128 + (ch << 4));
#pragma unroll
      for (int m = 0; m < 4; m++)
        acc[m][f] = __builtin_amdgcn_mfma_f32_16x16x32_bf16(av[m], bv, acc[m][f], 0, 0, 0);
    }
  }
  // ---- epilogue: (lin+bl)*mask*sigm(gate+blg) -> Lbuf f32
#pragma unroll
  for (int fp = 0; fp < 2; fp++) {
    const int h = wave * 32 + fp * 16 + l15;
    const float blv = bl[h], blgv = blg[h];
#pragma unroll
    for (int m = 0; m < 4; m++) {
      f32x4 lin = acc[m][fp];
      f32x4 gat = acc[m][2 + fp];
#pragma unroll
      for (int r = 0; r < 4; r++) {
        const int g = g0 + m * 16 + l4 * 4 + r;
        const int i = g / 9, d = g - 9 * i;
        const int p = i + d - 4;
        const bool valid = (p >= 0) && (p < LL);
        const float mv = valid ? (float)smask[i] * (float)smask[valid ? p : 0] : 0.f;
        Lbuf[(size_t)g * HIDC + h] = (lin[r] + blv) * mv * sigm(gat[r] + blgv);
      }
    }
  }
}

// ---- kernel B: banded product + LN + gate + Wo proj (round-4, unchanged)
// og aliases d_out; each block reads only its own (i, j-tile) og rows and
// overwrites exactly those rows with the final output (ordered by barrier).
extern "C" __global__ void __launch_bounds__(256, 4)
kernB(const u16* __restrict__ ring, const u16* og,
      const float* __restrict__ Lbuf, const u16* __restrict__ WoT,
      const float* __restrict__ osc, const float* __restrict__ obi,
      const float* __restrict__ bo, float* out, int k0, int i0)
{
  __shared__ u16 sWo[64 * 128];   // 16KB swizzled image
  __shared__ u16 sA[64 * 128];    // 16KB swizzled
  __shared__ float sLb[9 * 128];
  const int bid = blockIdx.x;
  const int i = i0 + (bid >> 3), j0 = (bid & 7) * 64;
  const int t = threadIdx.x;
  const int lane = t & 63, wave = t >> 6;
  const int l15 = lane & 15, l4 = lane >> 4;
  { // stage Wo: linear uint4 copy of pre-swizzled image
    const uint4* src = (const uint4*)WoT;
    uint4* dst = (uint4*)sWo;
#pragma unroll
    for (int c = 0; c < 4; ++c) dst[t + c * 256] = src[t + c * 256];
    const float* lb = Lbuf + (size_t)i * (9 * HIDC);
    for (int idx = t; idx < 9 * HIDC; idx += 256) sLb[idx] = lb[idx];
  }
  __syncthreads();
  const int j = t >> 2, hq = t & 3, h0 = hq * 32;
  float acc[32];
#pragma unroll
  for (int e = 0; e < 32; e++) acc[e] = 0.f;
  for (int d = 0; d < 9; d++) {
    const int k = i + d - 4;
    if (k < 0 || k >= LL) continue;
    const int slot = k - k0;
    const u16* rp = ring + ((size_t)slot * LL + j0 + j) * HIDC + h0;
#pragma unroll
    for (int c4 = 0; c4 < 4; c4++) {
      uint4 rv = *(const uint4*)(rp + c4 * 8);
      const float4 lb0 = *(const float4*)(sLb + d * 128 + h0 + c4 * 8);
      const float4 lb1 = *(const float4*)(sLb + d * 128 + h0 + c4 * 8 + 4);
      acc[c4*8+0] = fmaf(lb0.x, bf2f(rv.x & 0xffff), acc[c4*8+0]);
      acc[c4*8+1] = fmaf(lb0.y, bf2f(rv.x >> 16),    acc[c4*8+1]);
      acc[c4*8+2] = fmaf(lb0.z, bf2f(rv.y & 0xffff), acc[c4*8+2]);
      acc[c4*8+3] = fmaf(lb0.w, bf2f(rv.y >> 16),    acc[c4*8+3]);
      acc[c4*8+4] = fmaf(lb1.x, bf2f(rv.z & 0xffff), acc[c4*8+4]);
      acc[c4*8+5] = fmaf(lb1.y, bf2f(rv.z >> 16),    acc[c4*8+5]);
      acc[c4*8+6] = fmaf(lb1.z, bf2f(rv.w & 0xffff), acc[c4*8+6]);
      acc[c4*8+7] = fmaf(lb1.w, bf2f(rv.w >> 16),    acc[c4*8+7]);
    }
  }
  // LN over 128 (4 threads per j)
  float s = 0.f, ss = 0.f;
#pragma unroll
  for (int e = 0; e < 32; e++) { s += acc[e]; ss += acc[e] * acc[e]; }
  s += __shfl_xor(s, 1); ss += __shfl_xor(ss, 1);
  s += __shfl_xor(s, 2); ss += __shfl_xor(ss, 2);
  const float mean = s * (1.f / 128.f);
  const float rstd = rsqrtf(ss * (1.f / 128.f) - mean * mean + 1e-6f);
  const u16* ogp = og + ((size_t)i * LL + j0 + j) * HIDC + h0;
  char* rowp = (char*)sA + j * 256;
#pragma unroll
  for (int c4 = 0; c4 < 4; c4++) {
    const float4 o0 = *(const float4*)(osc + h0 + c4 * 8);
    const float4 o1 = *(const float4*)(osc + h0 + c4 * 8 + 4);
    const float4 b0 = *(const float4*)(obi + h0 + c4 * 8);
    const float4 b1 = *(const float4*)(obi + h0 + c4 * 8 + 4);
    uint4 gv = *(const uint4*)(ogp + c4 * 8);
    float v0 = ((acc[c4*8+0] - mean) * rstd * o0.x + b0.x) * bf2f(gv.x & 0xffff);
    float v1 = ((acc[c4*8+1] - mean) * rstd * o0.y + b0.y) * bf2f(gv.x >> 16);
    float v2 = ((acc[c4*8+2] - mean) * rstd * o0.z + b0.z) * bf2f(gv.y & 0xffff);
    float v3 = ((acc[c4*8+3] - mean) * rstd * o0.w + b0.w) * bf2f(gv.y >> 16);
    float v4 = ((acc[c4*8+4] - mean) * rstd * o1.x + b1.x) * bf2f(gv.z & 0xffff);
    float v5 = ((acc[c4*8+5] - mean) * rstd * o1.y + b1.y) * bf2f(gv.z >> 16);
    float v6 = ((acc[c4*8+6] - mean) * rstd * o1.z + b1.z) * bf2f(gv.w & 0xffff);
    float v7 = ((acc[c4*8+7] - mean) * rstd * o1.w + b1.w) * bf2f(gv.w >> 16);
    uint4 pk;
    pk.x = (u32)f2bf(v0) | ((u32)f2bf(v1) << 16);
    pk.y = (u32)f2bf(v2) | ((u32)f2bf(v3) << 16);
    pk.z = (u32)f2bf(v4) | ((u32)f2bf(v5) << 16);
    pk.w = (u32)f2bf(v6) | ((u32)f2bf(v7) << 16);
    *(uint4*)(rowp + (((hq * 4 + c4) ^ (j & 7)) << 4)) = pk;
  }
  __syncthreads();   // og fully read; sA ready
  f32x4 acc2[4];
  f32x4 zero = {0.f, 0.f, 0.f, 0.f};
#pragma unroll
  for (int m = 0; m < 4; m++) acc2[m] = zero;
#pragma unroll
  for (int ks = 0; ks < 4; ks++) {
    int n = wave * 16 + l15;
    int chb = (ks * 4 + l4) ^ (n & 7);
    bf16x8 bv = *(const bf16x8*)((const char*)sWo + n * 256 + (chb << 4));
#pragma unroll
    for (int m = 0; m < 4; m++) {
      int row = m * 16 + l15;
      int cha = (ks * 4 + l4) ^ (row & 7);
      bf16x8 av = *(const bf16x8*)((const char*)sA + row * 256 + (cha << 4));
      acc2[m] = __builtin_amdgcn_mfma_f32_16x16x32_bf16(av, bv, acc2[m], 0, 0, 0);
    }
  }
  const int dim = wave * 16 + l15;
  const float bov = bo[dim];
#pragma unroll
  for (int m = 0; m < 4; m++) {
#pragma unroll
    for (int r = 0; r < 4; r++) {
      int jj = j0 + m * 16 + l4 * 4 + r;
      out[((size_t)i * LL + jj) * DIMC + dim] = acc2[m][r] + bov;
    }
  }
}

extern "C" void kernel_launch(void* const* d_in, const int* in_sizes, int n_in,
                              void* d_out, int out_size, void* d_ws, size_t ws_size,
                              hipStream_t stream) {
  const float* x    = (const float*)d_in[0];
  const int*   sm   = (const int*)d_in[1];
  const float* ns   = (const float*)d_in[2];
  const float* nb   = (const float*)d_in[3];
  const float* Wl   = (const float*)d_in[4];
  const float* bl   = (const float*)d_in[5];
  const float* Wr   = (const float*)d_in[6];
  const float* br   = (const float*)d_in[7];
  const float* Wlg  = (const float*)d_in[8];
  const float* blg  = (const float*)d_in[9];
  const float* Wrg  = (const float*)d_in[10];
  const float* brg  = (const float*)d_in[11];
  const float* Wog  = (const float*)d_in[12];
  const float* bog  = (const float*)d_in[13];
  const float* osc  = (const float*)d_in[14];
  const float* obi  = (const float*)d_in[15];
  const float* Wo   = (const float*)d_in[16];
  const float* bo   = (const float*)d_in[17];

  // ws layout: Lbuf f32 | WTr 48KB | WTl 32KB | WoT 16KB | ring.
  const size_t LBUF_BYTES = (size_t)LL * 9 * HIDC * 4;   // 2,359,296
  char* ws = (char*)d_ws;
  float* Lbuf = (float*)ws;
  u16* WTr = (u16*)(ws + LBUF_BYTES);
  u16* WTl = (u16*)(ws + LBUF_BYTES + 49152);
  u16* WoT = (u16*)(ws + LBUF_BYTES + 49152 + 32768);
  u16* ring = (u16*)(ws + LBUF_BYTES + 49152 + 32768 + 16384);

  int CHUNK = 256;
  if (ws_size < LBUF_BYTES + 98304 + (size_t)(256 + 8) * LL * HIDC * 2) CHUNK = 64;
  u16* ogB = (u16*)d_out;   // og lives in d_out, chunk-local, consumed by kernB

  prep<<<32, 256, 0, stream>>>(Wr, Wrg, Wog, Wl, Wlg, Wo, WTr, WTl, WoT);
  kernL<<<72, 256, 0, stream>>>(x, sm, ns, nb, bl, blg, WTl, Lbuf);
  for (int i0 = 0; i0 < LL; i0 += CHUNK) {
    const int k0 = i0 - 4;
    kernA<<<(CHUNK + 8) * 8, 256, 0, stream>>>(x, sm, ns, nb, br, brg, bog,
                                               WTr, ring, ogB, k0, i0, CHUNK);
    kernB<<<CHUNK * 8, 256, 0, stream>>>(ring, ogB, Lbuf, WoT, osc, obi, bo,
                                         (float*)d_out, k0, i0);
  }
}